// Round 1
// baseline (430.041 us; speedup 1.0000x reference)
//
#include <hip/hip_runtime.h>

// Haar inverse DWT2 (db1), fp32.
// Inputs: A, H, V, D each [8,32,256,256] fp32 (flat 16,777,216 elems).
// Output: [8,32,512,512] fp32 (flat 67,108,864 elems).
// x[2i,2j]   = (A+H+V+D)/2    x[2i,2j+1] = (A+H-V-D)/2
// x[2i+1,2j] = (A-H+V-D)/2    x[2i+1,2j+1] = (A-H-V+D)/2

#define IN_H 256
#define IN_W 256
#define N_IMG (8 * 32)
#define PAIRS_PER_ROW (IN_W / 2)              // 128 = 2^7
#define PAIRS_PER_IMG (IN_H * PAIRS_PER_ROW)  // 32768 = 2^15
#define TOTAL_PAIRS (N_IMG * PAIRS_PER_IMG)   // 8,388,608

__global__ __launch_bounds__(256) void idwt2_haar_kernel(
    const float* __restrict__ A, const float* __restrict__ Hc,
    const float* __restrict__ V, const float* __restrict__ D,
    float* __restrict__ out) {
  int p = blockIdx.x * blockDim.x + threadIdx.x;  // global pair index
  if (p >= TOTAL_PAIRS) return;

  // pair layout matches flat float2 layout of the inputs
  const float2 a = ((const float2*)A)[p];
  const float2 h = ((const float2*)Hc)[p];
  const float2 v = ((const float2*)V)[p];
  const float2 d = ((const float2*)D)[p];

  // element 0 (input col 2j)
  float lp0 = a.x + h.x, lm0 = a.x - h.x;
  float mp0 = v.x + d.x, mm0 = v.x - d.x;
  // element 1 (input col 2j+1)
  float lp1 = a.y + h.y, lm1 = a.y - h.y;
  float mp1 = v.y + d.y, mm1 = v.y - d.y;

  float4 row_even, row_odd;
  row_even.x = 0.5f * (lp0 + mp0);
  row_even.y = 0.5f * (lp0 - mp0);
  row_even.z = 0.5f * (lp1 + mp1);
  row_even.w = 0.5f * (lp1 - mp1);
  row_odd.x = 0.5f * (lm0 + mm0);
  row_odd.y = 0.5f * (lm0 - mm0);
  row_odd.z = 0.5f * (lm1 + mm1);
  row_odd.w = 0.5f * (lm1 - mm1);

  int j = p & (PAIRS_PER_ROW - 1);        // 0..127
  int i = (p >> 7) & (IN_H - 1);          // 0..255
  int img = p >> 15;

  size_t obase =
      ((size_t)img * (2 * IN_H) + 2 * (size_t)i) * (2 * IN_W) + 4 * (size_t)j;
  *(float4*)(out + obase) = row_even;             // row 2i, cols 4j..4j+3
  *(float4*)(out + obase + 2 * IN_W) = row_odd;   // row 2i+1
}

extern "C" void kernel_launch(void* const* d_in, const int* in_sizes, int n_in,
                              void* d_out, int out_size, void* d_ws,
                              size_t ws_size, hipStream_t stream) {
  const float* A = (const float*)d_in[0];
  const float* Hc = (const float*)d_in[1];
  const float* V = (const float*)d_in[2];
  const float* D = (const float*)d_in[3];
  float* out = (float*)d_out;

  const int threads = 256;
  const int blocks = TOTAL_PAIRS / threads;  // 32768
  idwt2_haar_kernel<<<blocks, threads, 0, stream>>>(A, Hc, V, D, out);
}